// Round 6
// baseline (916.560 us; speedup 1.0000x reference)
//
#include <hip/hip_runtime.h>

#define N_PTS  (4*1024*1024)
#define NCLUST 65536

// ---------------------------------------------------------------------------
// Kernel 0: zero-fill pooled (ws is re-poisoned 0xAA before every launch).
// ---------------------------------------------------------------------------
__global__ __launch_bounds__(256) void k_zero(float4* __restrict__ p)
{
    p[(size_t)blockIdx.x * 256 + threadIdx.x] = make_float4(0.f, 0.f, 0.f, 0.f);
}

// ---------------------------------------------------------------------------
// Kernel 1: fc0 (3->64) + ReLU + sorted segment-max pool, broadcast-free.
// Lane decomposition: lane = fg*16 + p  (fg = feature group 0..3, p = point
// slot 0..15). Each lane computes 16 features of ITS OWN point -> point data
// comes in via coalesced vector loads; W0 is register-resident per lane
// (static-indexed arrays only — R4 lesson: dynamic indexing => scratch).
// Pooling: per-lane running vmax while tiles are run-uniform; on run change,
// 4-round shfl_xor butterfly (within the 16-lane p-group) + atomicMax from
// p==0 lanes only. Non-uniform tiles: per-sub-run masked butterfly —
// contributing 0 to any cluster is harmless since all pooled values >= 0.
// atomicMax on uint bits == float max for values >= 0 (we relu first).
// ---------------------------------------------------------------------------
__global__ __launch_bounds__(256) void k_fc0_pool(
        const float* __restrict__ pts,          // [N,3]
        const int* __restrict__ clus,           // [N] sorted int32, < NCLUST
        const float* __restrict__ W0,           // [3,64]
        const float* __restrict__ b0,           // [64]
        float* __restrict__ pooled)             // [NCLUST,64], pre-zeroed
{
    const int tid  = threadIdx.x;
    const int lane = tid & 63;
    const int p    = lane & 15;          // point slot in tile
    const int fg   = lane >> 4;          // feature group (feats fg*16..+16)
    const int wv   = blockIdx.x * 4 + (tid >> 6);
    const int base = wv * 256;           // this wave owns 256 points

    // W0 columns for my feature group — fully static indexing => registers
    float w0x[16], w0y[16], w0z[16], w0b[16];
    #pragma unroll
    for (int r = 0; r < 16; ++r) {
        w0x[r] = W0[      fg * 16 + r];
        w0y[r] = W0[ 64 + fg * 16 + r];
        w0z[r] = W0[128 + fg * 16 + r];
        w0b[r] = b0[      fg * 16 + r];
    }

    float vmax[16];
    #pragma unroll
    for (int r = 0; r < 16; ++r) vmax[r] = 0.0f;

    unsigned* pool_u = (unsigned*)pooled;
    int cur = __builtin_amdgcn_readfirstlane(clus[base]);

    // butterfly-max vmax over the 16 p-lanes, atomic from p==0, reset vmax
#define FLUSH(RID) { \
    _Pragma("unroll") \
    for (int r = 0; r < 16; ++r) { \
        float v = vmax[r]; \
        v = fmaxf(v, __shfl_xor(v, 1)); \
        v = fmaxf(v, __shfl_xor(v, 2)); \
        v = fmaxf(v, __shfl_xor(v, 4)); \
        v = fmaxf(v, __shfl_xor(v, 8)); \
        vmax[r] = v; } \
    if (p == 0) { \
        _Pragma("unroll") \
        for (int r = 0; r < 16; ++r) \
            atomicMax(&pool_u[(size_t)(RID) * 64 + fg * 16 + r], \
                      __float_as_uint(vmax[r])); } \
    _Pragma("unroll") \
    for (int r = 0; r < 16; ++r) vmax[r] = 0.0f; }

    #pragma unroll 1
    for (int t = 0; t < 16; ++t) {
        const int tb = base + t * 16;
        const int c  = clus[tb + p];                       // my slot's id
        const int c0 = __builtin_amdgcn_readfirstlane(c);
        const unsigned long long match0 = __ballot(c == c0);
        const bool uni = (match0 == ~0ULL);

        // my point (coalesced: 16 slots x 12B, 4-way fg redundancy -> L1)
        const size_t o = (size_t)(tb + p) * 3;
        const float px = pts[o], py = pts[o + 1], pz = pts[o + 2];
        float h[16];
        #pragma unroll
        for (int r = 0; r < 16; ++r)
            h[r] = fmaf(px, w0x[r], fmaf(py, w0y[r], fmaf(pz, w0z[r], w0b[r])));

        if (uni) {
            if (c0 != cur) { FLUSH(cur); cur = c0; }
            #pragma unroll
            for (int r = 0; r < 16; ++r) vmax[r] = fmaxf(vmax[r], h[r]);
        } else {
            FLUSH(cur);
            // walk sub-runs; out-of-run lanes contribute 0 (harmless)
            int start = 0;
            int rid = c0;
            unsigned long long m = match0;
            #pragma unroll 1
            while (true) {
                #pragma unroll
                for (int r = 0; r < 16; ++r) {
                    float v = (c == rid) ? fmaxf(h[r], 0.0f) : 0.0f;
                    v = fmaxf(v, __shfl_xor(v, 1));
                    v = fmaxf(v, __shfl_xor(v, 2));
                    v = fmaxf(v, __shfl_xor(v, 4));
                    v = fmaxf(v, __shfl_xor(v, 8));
                    if (p == 0)
                        atomicMax(&pool_u[(size_t)rid * 64 + fg * 16 + r],
                                  __float_as_uint(v));
                }
                start += (int)(__popcll(m) >> 2);   // slots in this run (/4 fg)
                if (start >= 16) break;
                rid = __builtin_amdgcn_readlane(c, start);
                m = __ballot(c == rid);
            }
            cur = __builtin_amdgcn_readlane(c, 15); // continue with last id
            // vmax already zeroed by FLUSH
        }
    }
    FLUSH(cur);
#undef FLUSH
}

// ---------------------------------------------------------------------------
// Kernel 2: fused fc1+fc2, lane = row, weights via scalar (uniform) loads.
// Block = 64 cluster rows x 512 threads (8 waves). (unchanged — next target)
// ---------------------------------------------------------------------------
__global__ __launch_bounds__(512, 6) void k_mlp(
        const float* __restrict__ pooled,
        const float* __restrict__ W1,
        const float* __restrict__ b1,
        const float* __restrict__ W2,
        const float* __restrict__ b2,
        float* __restrict__ out)
{
    __shared__ float Ps[64 * 65];
    __shared__ float Hs[64 * 129];

    const int tid  = threadIdx.x;
    const int lane = tid & 63;                                   // row
    const int w    = __builtin_amdgcn_readfirstlane(tid >> 6);   // wave 0..7
    const int r0b  = blockIdx.x * 64;

    {
        const float4* src = (const float4*)(pooled + (size_t)r0b * 64);
        #pragma unroll
        for (int j = 0; j < 2; ++j) {
            const int m  = tid + 512 * j;
            const float4 v = src[m];
            const int r = m >> 4, c4 = m & 15;
            float* d = &Ps[r * 65 + c4 * 4];
            d[0] = v.x; d[1] = v.y; d[2] = v.z; d[3] = v.w;
        }
    }
    __syncthreads();

    // ---------------- Phase A: fc1 -> Hs ----------------
    {
        const int cb = w * 16;
        float accA[16];
        #pragma unroll
        for (int j = 0; j < 4; ++j) {
            const float4 b = *(const float4*)(b1 + cb + 4 * j);
            accA[4*j+0] = b.x; accA[4*j+1] = b.y; accA[4*j+2] = b.z; accA[4*j+3] = b.w;
        }
        #pragma unroll 2
        for (int k = 0; k < 64; ++k) {
            const float h = Ps[lane * 65 + k];
            const float4 wa = *(const float4*)(W1 + k * 128 + cb);
            const float4 wb = *(const float4*)(W1 + k * 128 + cb + 4);
            const float4 wc = *(const float4*)(W1 + k * 128 + cb + 8);
            const float4 wd = *(const float4*)(W1 + k * 128 + cb + 12);
            accA[ 0] = fmaf(h, wa.x, accA[ 0]);
            accA[ 1] = fmaf(h, wa.y, accA[ 1]);
            accA[ 2] = fmaf(h, wa.z, accA[ 2]);
            accA[ 3] = fmaf(h, wa.w, accA[ 3]);
            accA[ 4] = fmaf(h, wb.x, accA[ 4]);
            accA[ 5] = fmaf(h, wb.y, accA[ 5]);
            accA[ 6] = fmaf(h, wb.z, accA[ 6]);
            accA[ 7] = fmaf(h, wb.w, accA[ 7]);
            accA[ 8] = fmaf(h, wc.x, accA[ 8]);
            accA[ 9] = fmaf(h, wc.y, accA[ 9]);
            accA[10] = fmaf(h, wc.z, accA[10]);
            accA[11] = fmaf(h, wc.w, accA[11]);
            accA[12] = fmaf(h, wd.x, accA[12]);
            accA[13] = fmaf(h, wd.y, accA[13]);
            accA[14] = fmaf(h, wd.z, accA[14]);
            accA[15] = fmaf(h, wd.w, accA[15]);
        }
        #pragma unroll
        for (int j = 0; j < 16; ++j)
            Hs[lane * 129 + cb + j] = fmaxf(accA[j], 0.0f);
    }
    __syncthreads();

    // ---------------- Phase B: fc2 ----------------
    float acc[32];
    const int cb2 = w * 32;
    #pragma unroll
    for (int j = 0; j < 8; ++j) {
        const float4 b = *(const float4*)(b2 + cb2 + 4 * j);
        acc[4*j+0] = b.x; acc[4*j+1] = b.y; acc[4*j+2] = b.z; acc[4*j+3] = b.w;
    }
    #pragma unroll 2
    for (int k = 0; k < 128; ++k) {
        const float h = Hs[lane * 129 + k];
        #pragma unroll
        for (int j = 0; j < 8; ++j) {
            const float4 wv = *(const float4*)(W2 + (size_t)k * 256 + cb2 + 4 * j);
            acc[4*j+0] = fmaf(h, wv.x, acc[4*j+0]);
            acc[4*j+1] = fmaf(h, wv.y, acc[4*j+1]);
            acc[4*j+2] = fmaf(h, wv.z, acc[4*j+2]);
            acc[4*j+3] = fmaf(h, wv.w, acc[4*j+3]);
        }
    }
    #pragma unroll
    for (int j = 0; j < 32; ++j) acc[j] = fmaxf(acc[j], 0.0f);

    // ---- epilogue: transpose via Hs, coalesced float4 stores (2 sweeps) ----
    #pragma unroll 1
    for (int s = 0; s < 2; ++s) {
        __syncthreads();
        if ((w >> 2) == s) {
            const int cl = cb2 - s * 128;
            #pragma unroll
            for (int j = 0; j < 32; ++j)
                Hs[lane * 129 + cl + j] = acc[j];
        }
        __syncthreads();
        #pragma unroll
        for (int it = 0; it < 4; ++it) {
            const int m = tid + 512 * it;
            const int r = m >> 5, c4 = m & 31;
            float4 o;
            o.x = Hs[r * 129 + c4 * 4 + 0];
            o.y = Hs[r * 129 + c4 * 4 + 1];
            o.z = Hs[r * 129 + c4 * 4 + 2];
            o.w = Hs[r * 129 + c4 * 4 + 3];
            *(float4*)(out + (size_t)(r0b + r) * 256 + s * 128 + c4 * 4) = o;
        }
    }
}

// ---------------------------------------------------------------------------
extern "C" void kernel_launch(void* const* d_in, const int* in_sizes, int n_in,
                              void* d_out, int out_size, void* d_ws, size_t ws_size,
                              hipStream_t stream) {
    const float* points  = (const float*)d_in[0];
    const int*   cluster = (const int*)d_in[1];   // int32 on device (harness)
    const float* W0      = (const float*)d_in[2];
    const float* b0      = (const float*)d_in[3];
    const float* W1      = (const float*)d_in[4];
    const float* b1      = (const float*)d_in[5];
    const float* W2      = (const float*)d_in[6];
    const float* b2      = (const float*)d_in[7];
    float* out = (float*)d_out;

    float* pooled = (float*)d_ws;   // 16 MB

    k_zero<<<(NCLUST * 64 / 4) / 256, 256, 0, stream>>>((float4*)pooled);
    k_fc0_pool<<<N_PTS / 1024, 256, 0, stream>>>(points, cluster, W0, b0, pooled);
    k_mlp<<<NCLUST / 64, 512, 0, stream>>>(pooled, W1, b1, W2, b2, out);
}

// Round 7
// 253.105 us; speedup vs baseline: 3.6213x; 3.6213x over previous
//
#include <hip/hip_runtime.h>

#define N_PTS  (4*1024*1024)
#define NCLUST 65536

// ---------------------------------------------------------------------------
// Kernel 0: zero-fill pooled (ws is re-poisoned 0xAA before every launch).
// ---------------------------------------------------------------------------
__global__ __launch_bounds__(256) void k_zero(float4* __restrict__ p)
{
    p[(size_t)blockIdx.x * 256 + threadIdx.x] = make_float4(0.f, 0.f, 0.f, 0.f);
}

// ---------------------------------------------------------------------------
// Kernel 1: fc0 (3->64) + ReLU + sorted segment-max pool.
// Wave = 64 lanes = 64 features; wave owns 256 points in 4 rounds of 64.
// Delivery mechanism (R3: LDS b128 broadcast = 12cyc/pt on the per-CU LDS
// pipe -> 82us floor; R5: scalar K$ serialization -> 147us; R6: shfl
// butterfly = ds_swizzle on LDS pipe + 20x atomics -> 750us):
// stage points INTO LANES (coalesced 12B/lane), broadcast via v_readlane
// (VALU, per-SIMD) -> 3 readlane + 3 FMA + 1 max per point, no LDS pipe.
// Pooling: per-lane running vmax; run change -> ONE atomicMax instruction
// (all 64 lanes store their feature). pooled pre-zeroed; ReLU>=0 makes 0
// the max-identity and empty-cluster fill; uint-bits max == float max >=0.
// ---------------------------------------------------------------------------
__global__ __launch_bounds__(256) void k_fc0_pool(
        const float* __restrict__ pts,          // [N,3]
        const int* __restrict__ clus,           // [N] sorted int32, < NCLUST
        const float* __restrict__ W0,           // [3,64]
        const float* __restrict__ b0,           // [64]
        float* __restrict__ pooled)             // [NCLUST,64], pre-zeroed
{
    const int tid  = threadIdx.x;
    const int lane = tid & 63;
    const int w    = tid >> 6;                    // wave 0..3 (uniform)
    const int base = blockIdx.x * 1024 + w * 256; // uniform per wave

    const float w0x = W0[lane];
    const float w0y = W0[64 + lane];
    const float w0z = W0[128 + lane];
    const float bb  = b0[lane];

    unsigned* pool_u = (unsigned*)pooled;
    int   cur  = clus[base];                      // uniform -> scalar load
    float vmax = 0.0f;

#define FLUSH(RID) { \
    atomicMax(&pool_u[(size_t)(RID) * 64 + lane], __float_as_uint(vmax)); \
    vmax = 0.0f; }

#define RL_F(v, i) __uint_as_float(__builtin_amdgcn_readlane(__float_as_uint(v), (i)))

    #pragma unroll 1
    for (int rnd = 0; rnd < 4; ++rnd) {
        const int rb = base + rnd * 64;           // uniform
        // stage: lane l holds point rb+l (12B/lane, contiguous 768B/wave)
        const float* ps = pts + (size_t)rb * 3;
        const float vx = ps[lane * 3 + 0];
        const float vy = ps[lane * 3 + 1];
        const float vz = ps[lane * 3 + 2];
        const int   vc = clus[rb + lane];

        #pragma unroll
        for (int ch = 0; ch < 4; ++ch) {
            const int i0 = ch * 16;
            const int cf = __builtin_amdgcn_readlane(vc, i0);
            const int cl = __builtin_amdgcn_readlane(vc, i0 + 15);
            if (cf == cl) {                       // chunk = single run
                if (cf != cur) { FLUSH(cur); cur = cf; }
                float m0 = vmax, m1 = vmax, m2 = vmax, m3 = vmax;
                #pragma unroll
                for (int t = 0; t < 16; t += 4) {
                    const float ax = RL_F(vx, i0 + t),     ay = RL_F(vy, i0 + t),     az = RL_F(vz, i0 + t);
                    const float bx = RL_F(vx, i0 + t + 1), by = RL_F(vy, i0 + t + 1), bz = RL_F(vz, i0 + t + 1);
                    const float cx = RL_F(vx, i0 + t + 2), cy = RL_F(vy, i0 + t + 2), cz = RL_F(vz, i0 + t + 2);
                    const float dx = RL_F(vx, i0 + t + 3), dy = RL_F(vy, i0 + t + 3), dz = RL_F(vz, i0 + t + 3);
                    m0 = fmaxf(m0, fmaf(ax, w0x, fmaf(ay, w0y, fmaf(az, w0z, bb))));
                    m1 = fmaxf(m1, fmaf(bx, w0x, fmaf(by, w0y, fmaf(bz, w0z, bb))));
                    m2 = fmaxf(m2, fmaf(cx, w0x, fmaf(cy, w0y, fmaf(cz, w0z, bb))));
                    m3 = fmaxf(m3, fmaf(dx, w0x, fmaf(dy, w0y, fmaf(dz, w0z, bb))));
                }
                vmax = fmaxf(fmaxf(m0, m1), fmaxf(m2, m3));
            } else {                              // boundary chunk: walk
                #pragma unroll 1
                for (int t = 0; t < 16; ++t) {
                    const int c = __builtin_amdgcn_readlane(vc, i0 + t); // SGPR idx ok
                    if (c != cur) { FLUSH(cur); cur = c; }
                    const float sx = RL_F(vx, i0 + t);
                    const float sy = RL_F(vy, i0 + t);
                    const float sz = RL_F(vz, i0 + t);
                    vmax = fmaxf(vmax, fmaf(sx, w0x, fmaf(sy, w0y, fmaf(sz, w0z, bb))));
                }
            }
        }
    }
    FLUSH(cur);
#undef FLUSH
#undef RL_F
}

// ---------------------------------------------------------------------------
// Kernel 2: fused fc1+fc2, lane = row, weights via scalar (uniform) loads.
// Block = 64 cluster rows x 512 threads (8 waves).
// Change vs R6: launch_bounds min-waves 6 -> 4 (the 6/EU floor capped the
// register allocator at ~85 VGPR; 4/EU allows 128 and 2 blocks/CU).
// ---------------------------------------------------------------------------
__global__ __launch_bounds__(512, 4) void k_mlp(
        const float* __restrict__ pooled,
        const float* __restrict__ W1,
        const float* __restrict__ b1,
        const float* __restrict__ W2,
        const float* __restrict__ b2,
        float* __restrict__ out)
{
    __shared__ float Ps[64 * 65];
    __shared__ float Hs[64 * 129];

    const int tid  = threadIdx.x;
    const int lane = tid & 63;                                   // row
    const int w    = __builtin_amdgcn_readfirstlane(tid >> 6);   // wave 0..7
    const int r0b  = blockIdx.x * 64;

    {
        const float4* src = (const float4*)(pooled + (size_t)r0b * 64);
        #pragma unroll
        for (int j = 0; j < 2; ++j) {
            const int m  = tid + 512 * j;
            const float4 v = src[m];
            const int r = m >> 4, c4 = m & 15;
            float* d = &Ps[r * 65 + c4 * 4];
            d[0] = v.x; d[1] = v.y; d[2] = v.z; d[3] = v.w;
        }
    }
    __syncthreads();

    // ---------------- Phase A: fc1 -> Hs ----------------
    {
        const int cb = w * 16;
        float accA[16];
        #pragma unroll
        for (int j = 0; j < 4; ++j) {
            const float4 b = *(const float4*)(b1 + cb + 4 * j);
            accA[4*j+0] = b.x; accA[4*j+1] = b.y; accA[4*j+2] = b.z; accA[4*j+3] = b.w;
        }
        #pragma unroll 2
        for (int k = 0; k < 64; ++k) {
            const float h = Ps[lane * 65 + k];
            const float4 wa = *(const float4*)(W1 + k * 128 + cb);
            const float4 wb = *(const float4*)(W1 + k * 128 + cb + 4);
            const float4 wc = *(const float4*)(W1 + k * 128 + cb + 8);
            const float4 wd = *(const float4*)(W1 + k * 128 + cb + 12);
            accA[ 0] = fmaf(h, wa.x, accA[ 0]);
            accA[ 1] = fmaf(h, wa.y, accA[ 1]);
            accA[ 2] = fmaf(h, wa.z, accA[ 2]);
            accA[ 3] = fmaf(h, wa.w, accA[ 3]);
            accA[ 4] = fmaf(h, wb.x, accA[ 4]);
            accA[ 5] = fmaf(h, wb.y, accA[ 5]);
            accA[ 6] = fmaf(h, wb.z, accA[ 6]);
            accA[ 7] = fmaf(h, wb.w, accA[ 7]);
            accA[ 8] = fmaf(h, wc.x, accA[ 8]);
            accA[ 9] = fmaf(h, wc.y, accA[ 9]);
            accA[10] = fmaf(h, wc.z, accA[10]);
            accA[11] = fmaf(h, wc.w, accA[11]);
            accA[12] = fmaf(h, wd.x, accA[12]);
            accA[13] = fmaf(h, wd.y, accA[13]);
            accA[14] = fmaf(h, wd.z, accA[14]);
            accA[15] = fmaf(h, wd.w, accA[15]);
        }
        #pragma unroll
        for (int j = 0; j < 16; ++j)
            Hs[lane * 129 + cb + j] = fmaxf(accA[j], 0.0f);
    }
    __syncthreads();

    // ---------------- Phase B: fc2 ----------------
    float acc[32];
    const int cb2 = w * 32;
    #pragma unroll
    for (int j = 0; j < 8; ++j) {
        const float4 b = *(const float4*)(b2 + cb2 + 4 * j);
        acc[4*j+0] = b.x; acc[4*j+1] = b.y; acc[4*j+2] = b.z; acc[4*j+3] = b.w;
    }
    #pragma unroll 2
    for (int k = 0; k < 128; ++k) {
        const float h = Hs[lane * 129 + k];
        #pragma unroll
        for (int j = 0; j < 8; ++j) {
            const float4 wv = *(const float4*)(W2 + (size_t)k * 256 + cb2 + 4 * j);
            acc[4*j+0] = fmaf(h, wv.x, acc[4*j+0]);
            acc[4*j+1] = fmaf(h, wv.y, acc[4*j+1]);
            acc[4*j+2] = fmaf(h, wv.z, acc[4*j+2]);
            acc[4*j+3] = fmaf(h, wv.w, acc[4*j+3]);
        }
    }
    #pragma unroll
    for (int j = 0; j < 32; ++j) acc[j] = fmaxf(acc[j], 0.0f);

    // ---- epilogue: transpose via Hs, coalesced float4 stores (2 sweeps) ----
    #pragma unroll 1
    for (int s = 0; s < 2; ++s) {
        __syncthreads();
        if ((w >> 2) == s) {
            const int cl = cb2 - s * 128;
            #pragma unroll
            for (int j = 0; j < 32; ++j)
                Hs[lane * 129 + cl + j] = acc[j];
        }
        __syncthreads();
        #pragma unroll
        for (int it = 0; it < 4; ++it) {
            const int m = tid + 512 * it;
            const int r = m >> 5, c4 = m & 31;
            float4 o;
            o.x = Hs[r * 129 + c4 * 4 + 0];
            o.y = Hs[r * 129 + c4 * 4 + 1];
            o.z = Hs[r * 129 + c4 * 4 + 2];
            o.w = Hs[r * 129 + c4 * 4 + 3];
            *(float4*)(out + (size_t)(r0b + r) * 256 + s * 128 + c4 * 4) = o;
        }
    }
}

// ---------------------------------------------------------------------------
extern "C" void kernel_launch(void* const* d_in, const int* in_sizes, int n_in,
                              void* d_out, int out_size, void* d_ws, size_t ws_size,
                              hipStream_t stream) {
    const float* points  = (const float*)d_in[0];
    const int*   cluster = (const int*)d_in[1];   // int32 on device (harness)
    const float* W0      = (const float*)d_in[2];
    const float* b0      = (const float*)d_in[3];
    const float* W1      = (const float*)d_in[4];
    const float* b1      = (const float*)d_in[5];
    const float* W2      = (const float*)d_in[6];
    const float* b2      = (const float*)d_in[7];
    float* out = (float*)d_out;

    float* pooled = (float*)d_ws;   // 16 MB

    k_zero<<<(NCLUST * 64 / 4) / 256, 256, 0, stream>>>((float4*)pooled);
    k_fc0_pool<<<N_PTS / 1024, 256, 0, stream>>>(points, cluster, W0, b0, pooled);
    k_mlp<<<NCLUST / 64, 512, 0, stream>>>(pooled, W1, b1, W2, b2, out);
}